// Round 1
// baseline (935.220 us; speedup 1.0000x reference)
//
#include <hip/hip_runtime.h>
#include <math.h>

// Problem constants
#define NB 16384      // batch rows
#define NF 32         // features
#define ND 64         // dim
#define NIN 2048      // NF*ND

// ---------------------------------------------------------------------------
// helpers: cooperative loads into stride-65-padded LDS tiles (256 threads)
// ---------------------------------------------------------------------------
__device__ __forceinline__ void load_w64(const float* __restrict__ g,
                                         float* __restrict__ s, int tid) {
    // g: 64x64 row-major contiguous; s: 64 rows, stride 65
#pragma unroll
    for (int i = 0; i < 4; ++i) {
        int e = tid + i * 256;
        int r = e >> 4;
        int c4 = (e & 15) << 2;
        const float4 v = *(const float4*)(g + r * 64 + c4);
        float* p = s + r * 65 + c4;
        p[0] = v.x; p[1] = v.y; p[2] = v.z; p[3] = v.w;
    }
}

__device__ __forceinline__ void load_x64(const float* __restrict__ g,
                                         float* __restrict__ s, int tid) {
    // g: 64 rows with row stride NIN; s: stride 65
#pragma unroll
    for (int i = 0; i < 4; ++i) {
        int e = tid + i * 256;
        int r = e >> 4;
        int c4 = (e & 15) << 2;
        const float4 v = *(const float4*)(g + (size_t)r * NIN + c4);
        float* p = s + r * 65 + c4;
        p[0] = v.x; p[1] = v.y; p[2] = v.z; p[3] = v.w;
    }
}

// 64x64x64 GEMM tile: A (stride 65) x B (stride 65) -> 4x4 acc per thread
__device__ __forceinline__ void gemm_tile(const float* __restrict__ A,
                                          const float* __restrict__ Bm,
                                          int tr, int tc, float acc[4][4]) {
#pragma unroll 4
    for (int k = 0; k < 64; ++k) {
        float a[4], b[4];
#pragma unroll
        for (int rr = 0; rr < 4; ++rr) a[rr] = A[(tr + 16 * rr) * 65 + k];
#pragma unroll
        for (int cc = 0; cc < 4; ++cc) b[cc] = Bm[k * 65 + tc + 16 * cc];
#pragma unroll
        for (int rr = 0; rr < 4; ++rr)
#pragma unroll
            for (int cc = 0; cc < 4; ++cc) acc[rr][cc] += a[rr] * b[cc];
    }
}

// ---------------------------------------------------------------------------
// Kernel 1: mask branch.  64 rows per block, 256 threads.
// flat@[mw1|mlw] streamed over K in 64-chunks; small GEMMs + LN + softmax.
// ---------------------------------------------------------------------------
__global__ __launch_bounds__(256) void mask_kernel(
    const float* __restrict__ x,
    const float* __restrict__ mw1, const float* __restrict__ mb1,
    const float* __restrict__ mw2, const float* __restrict__ mb2,
    const float* __restrict__ mlw, const float* __restrict__ mlb,
    const float* __restrict__ mgw, const float* __restrict__ mgb,
    const float* __restrict__ mlw2, const float* __restrict__ mlb2,
    const float* __restrict__ mgamma, const float* __restrict__ mbeta,
    float* __restrict__ mask_out)
{
    __shared__ float xs[64 * 65];   // x chunk; reused as hs (elu'd h, 64 wide)
    __shared__ float wsh[64 * 96];  // weight chunk; reused: rs / h2s / pres

    const int tid = threadIdx.x;
    const int tr = tid >> 4;        // 0..15
    const int tc = tid & 15;        // 0..15
    const int row0 = blockIdx.x * 64;

    float acc[4][6];
#pragma unroll
    for (int rr = 0; rr < 4; ++rr)
#pragma unroll
        for (int cc = 0; cc < 6; ++cc) acc[rr][cc] = 0.f;

    for (int f = 0; f < NF; ++f) {
        __syncthreads();
        // x chunk (64 rows x 64 k)
        load_x64(x + (size_t)row0 * NIN + f * ND, xs, tid);
        // mw1 chunk -> wsh[:, 0:64]
#pragma unroll
        for (int i = 0; i < 4; ++i) {
            int e = tid + i * 256;
            int r = e >> 4;
            int c4 = (e & 15) << 2;
            const float4 v = *(const float4*)(mw1 + (size_t)(f * 64 + r) * 64 + c4);
            *(float4*)(&wsh[r * 96 + c4]) = v;
        }
        // mlw chunk -> wsh[:, 64:96]
#pragma unroll
        for (int i = 0; i < 2; ++i) {
            int e = tid + i * 256;
            int r = e >> 3;
            int c4 = (e & 7) << 2;
            const float4 v = *(const float4*)(mlw + (size_t)(f * 64 + r) * 32 + c4);
            *(float4*)(&wsh[r * 96 + 64 + c4]) = v;
        }
        __syncthreads();
#pragma unroll 4
        for (int k = 0; k < 64; ++k) {
            float a[4], b[6];
#pragma unroll
            for (int rr = 0; rr < 4; ++rr) a[rr] = xs[(tr + 16 * rr) * 65 + k];
#pragma unroll
            for (int cc = 0; cc < 6; ++cc) b[cc] = wsh[k * 96 + tc + 16 * cc];
#pragma unroll
            for (int rr = 0; rr < 4; ++rr)
#pragma unroll
                for (int cc = 0; cc < 6; ++cc) acc[rr][cc] += a[rr] * b[cc];
        }
    }
    __syncthreads();

    // write hs = elu(h1 + mb1) into xs;  rs = res into wsh[0:2048]
#pragma unroll
    for (int rr = 0; rr < 4; ++rr) {
        int r = tr + 16 * rr;
#pragma unroll
        for (int cc = 0; cc < 4; ++cc) {
            int c = tc + 16 * cc;
            float v = acc[rr][cc] + mb1[c];
            xs[r * 65 + c] = v > 0.f ? v : expm1f(v);
        }
#pragma unroll
        for (int cc = 4; cc < 6; ++cc) {
            int c = tc + 16 * (cc - 4);
            wsh[r * 32 + c] = acc[rr][cc] + mlb[c];
        }
    }
    __syncthreads();

    // h2 = hs @ mw2 + mb2  -> wsh[2048 + r*32 + c]
#pragma unroll
    for (int j = 0; j < 8; ++j) {
        int e = tid + j * 256;
        int r = e >> 5, c = e & 31;
        float s = mb2[c];
#pragma unroll 8
        for (int k = 0; k < 64; ++k) s += xs[r * 65 + k] * mw2[k * 32 + c];
        wsh[2048 + r * 32 + c] = s;
    }
    __syncthreads();

    // pre = sigmoid(h2@mgw + mgb) * (h2@mlw2 + mlb2) + rs  -> wsh[4096 + ...]
#pragma unroll
    for (int j = 0; j < 8; ++j) {
        int e = tid + j * 256;
        int r = e >> 5, c = e & 31;
        float g = mgb[c], l = mlb2[c];
#pragma unroll 8
        for (int k = 0; k < 32; ++k) {
            float hv = wsh[2048 + r * 32 + k];
            g += hv * mgw[k * 32 + c];
            l += hv * mlw2[k * 32 + c];
        }
        float sg = 1.f / (1.f + expf(-g));
        wsh[4096 + r * 32 + c] = sg * l + wsh[r * 32 + c];
    }
    __syncthreads();

    // per-row layernorm (F=32) + softmax
    if (tid < 64) {
        int r = tid;
        const float* p = &wsh[4096 + r * 32];
        float m = 0.f;
#pragma unroll
        for (int c = 0; c < 32; ++c) m += p[c];
        m *= (1.f / 32.f);
        float v = 0.f;
#pragma unroll
        for (int c = 0; c < 32; ++c) { float d = p[c] - m; v += d * d; }
        v *= (1.f / 32.f);
        float inv = rsqrtf(v + 1e-5f);
        float ln[32];
        float mx = -3.4e38f;
#pragma unroll
        for (int c = 0; c < 32; ++c) {
            ln[c] = (p[c] - m) * inv * mgamma[c] + mbeta[c];
            mx = fmaxf(mx, ln[c]);
        }
        float s = 0.f;
#pragma unroll
        for (int c = 0; c < 32; ++c) { float e2 = expf(ln[c] - mx); ln[c] = e2; s += e2; }
        float rs_ = 1.f / s;
        float* mo = mask_out + (size_t)(row0 + r) * 32;
#pragma unroll
        for (int c = 0; c < 32; ++c) mo[c] = ln[c] * rs_;
    }
}

// ---------------------------------------------------------------------------
// Kernel 2: per-feature GRNs + LN + mask-weighted sum.  64 rows/block.
// LDS: xs (x tile, later hh2), aA (hh, later lw), wS (current weight), ms.
// ---------------------------------------------------------------------------
__global__ __launch_bounds__(256) void grn_kernel(
    const float* __restrict__ x,
    const float* __restrict__ w1, const float* __restrict__ b1,
    const float* __restrict__ w2, const float* __restrict__ b2,
    const float* __restrict__ gw, const float* __restrict__ gb,
    const float* __restrict__ lw, const float* __restrict__ lb,
    const float* __restrict__ gamma, const float* __restrict__ beta,
    const float* __restrict__ mask,
    float* __restrict__ out)
{
    __shared__ float xs[64 * 65];
    __shared__ float aA[64 * 65];
    __shared__ float wS[64 * 65];
    __shared__ float ms[64 * 32];

    const int tid = threadIdx.x;
    const int tr = tid >> 4;
    const int tc = tid & 15;
    const int row0 = blockIdx.x * 64;

#pragma unroll
    for (int i = 0; i < 8; ++i) {
        int e = tid + i * 256;
        ms[e] = mask[(size_t)row0 * 32 + e];
    }

    float oacc[4][4];
#pragma unroll
    for (int rr = 0; rr < 4; ++rr)
#pragma unroll
        for (int cc = 0; cc < 4; ++cc) oacc[rr][cc] = 0.f;

    for (int f = 0; f < NF; ++f) {
        __syncthreads();  // protect xs/aA/wS from previous iteration readers
        load_x64(x + (size_t)row0 * NIN + f * ND, xs, tid);
        load_w64(w1 + (size_t)f * 4096, wS, tid);
        __syncthreads();

        // GEMM1: hh = elu(xs @ w1 + b1) -> aA
        {
            float acc[4][4];
#pragma unroll
            for (int rr = 0; rr < 4; ++rr)
#pragma unroll
                for (int cc = 0; cc < 4; ++cc) acc[rr][cc] = 0.f;
            gemm_tile(xs, wS, tr, tc, acc);
#pragma unroll
            for (int rr = 0; rr < 4; ++rr) {
                int r = tr + 16 * rr;
#pragma unroll
                for (int cc = 0; cc < 4; ++cc) {
                    int c = tc + 16 * cc;
                    float v = acc[rr][cc] + b1[f * 64 + c];
                    aA[r * 65 + c] = v > 0.f ? v : expm1f(v);
                }
            }
        }
        __syncthreads();
        load_w64(w2 + (size_t)f * 4096, wS, tid);
        __syncthreads();

        // GEMM2: hh2 = aA @ w2 + b2 -> xs (xs no longer needed as input)
        {
            float acc[4][4];
#pragma unroll
            for (int rr = 0; rr < 4; ++rr)
#pragma unroll
                for (int cc = 0; cc < 4; ++cc) acc[rr][cc] = 0.f;
            gemm_tile(aA, wS, tr, tc, acc);
#pragma unroll
            for (int rr = 0; rr < 4; ++rr) {
                int r = tr + 16 * rr;
#pragma unroll
                for (int cc = 0; cc < 4; ++cc) {
                    int c = tc + 16 * cc;
                    xs[r * 65 + c] = acc[rr][cc] + b2[f * 64 + c];
                }
            }
        }
        __syncthreads();
        load_w64(gw + (size_t)f * 4096, wS, tid);
        load_w64(lw + (size_t)f * 4096, aA, tid);
        __syncthreads();

        // GEMM3+4 fused: gate/lin pre-activations from xs (=hh2)
        float ga[4][4], la[4][4];
#pragma unroll
        for (int rr = 0; rr < 4; ++rr)
#pragma unroll
            for (int cc = 0; cc < 4; ++cc) { ga[rr][cc] = 0.f; la[rr][cc] = 0.f; }
#pragma unroll 2
        for (int k = 0; k < 64; ++k) {
            float a[4], bg[4], bl[4];
#pragma unroll
            for (int rr = 0; rr < 4; ++rr) a[rr] = xs[(tr + 16 * rr) * 65 + k];
#pragma unroll
            for (int cc = 0; cc < 4; ++cc) bg[cc] = wS[k * 65 + tc + 16 * cc];
#pragma unroll
            for (int cc = 0; cc < 4; ++cc) bl[cc] = aA[k * 65 + tc + 16 * cc];
#pragma unroll
            for (int rr = 0; rr < 4; ++rr)
#pragma unroll
                for (int cc = 0; cc < 4; ++cc) {
                    ga[rr][cc] += a[rr] * bg[cc];
                    la[rr][cc] += a[rr] * bl[cc];
                }
        }

        // epilogue: val = sigmoid(g)*l + x ; LN over D via 16-lane shuffles
#pragma unroll
        for (int rr = 0; rr < 4; ++rr) {
            int r = tr + 16 * rr;
            float val[4];
#pragma unroll
            for (int cc = 0; cc < 4; ++cc) {
                int c = tc + 16 * cc;
                float g = ga[rr][cc] + gb[f * 64 + c];
                float l = la[rr][cc] + lb[f * 64 + c];
                float resid = x[(size_t)(row0 + r) * NIN + f * ND + c];
                val[cc] = l * (1.f / (1.f + expf(-g))) + resid;
            }
            float s1 = val[0] + val[1] + val[2] + val[3];
            s1 += __shfl_xor(s1, 1);
            s1 += __shfl_xor(s1, 2);
            s1 += __shfl_xor(s1, 4);
            s1 += __shfl_xor(s1, 8);
            float mean = s1 * (1.f / 64.f);
            float s2 = 0.f;
#pragma unroll
            for (int cc = 0; cc < 4; ++cc) { float d = val[cc] - mean; s2 += d * d; }
            s2 += __shfl_xor(s2, 1);
            s2 += __shfl_xor(s2, 2);
            s2 += __shfl_xor(s2, 4);
            s2 += __shfl_xor(s2, 8);
            float inv = rsqrtf(s2 * (1.f / 64.f) + 1e-5f);
            float mk = ms[r * 32 + f];
#pragma unroll
            for (int cc = 0; cc < 4; ++cc) {
                int c = tc + 16 * cc;
                float vec = (val[cc] - mean) * inv * gamma[f * 64 + c] + beta[f * 64 + c];
                oacc[rr][cc] += mk * vec;
            }
        }
    }

#pragma unroll
    for (int rr = 0; rr < 4; ++rr) {
        int r = row0 + tr + 16 * rr;
#pragma unroll
        for (int cc = 0; cc < 4; ++cc) {
            out[(size_t)r * 64 + tc + 16 * cc] = oacc[rr][cc];
        }
    }
}

// ---------------------------------------------------------------------------
extern "C" void kernel_launch(void* const* d_in, const int* in_sizes, int n_in,
                              void* d_out, int out_size, void* d_ws, size_t ws_size,
                              hipStream_t stream) {
    const float* x      = (const float*)d_in[0];
    const float* mw1    = (const float*)d_in[1];
    const float* mb1    = (const float*)d_in[2];
    const float* mw2    = (const float*)d_in[3];
    const float* mb2    = (const float*)d_in[4];
    const float* mlw    = (const float*)d_in[5];
    const float* mlb    = (const float*)d_in[6];
    const float* mgw    = (const float*)d_in[7];
    const float* mgb    = (const float*)d_in[8];
    const float* mlw2   = (const float*)d_in[9];
    const float* mlb2   = (const float*)d_in[10];
    const float* mgamma = (const float*)d_in[11];
    const float* mbeta  = (const float*)d_in[12];
    const float* w1     = (const float*)d_in[13];
    const float* b1     = (const float*)d_in[14];
    const float* w2     = (const float*)d_in[15];
    const float* b2     = (const float*)d_in[16];
    const float* gw     = (const float*)d_in[17];
    const float* gb     = (const float*)d_in[18];
    const float* lw     = (const float*)d_in[19];
    const float* lb     = (const float*)d_in[20];
    const float* gamma  = (const float*)d_in[21];
    const float* beta   = (const float*)d_in[22];

    float* out  = (float*)d_out;                 // [B,64]
    float* mask = out + (size_t)NB * 64;         // [B,32] (second output)

    hipLaunchKernelGGL(mask_kernel, dim3(NB / 64), dim3(256), 0, stream,
                       x, mw1, mb1, mw2, mb2, mlw, mlb, mgw, mgb, mlw2, mlb2,
                       mgamma, mbeta, mask);
    hipLaunchKernelGGL(grn_kernel, dim3(NB / 64), dim3(256), 0, stream,
                       x, w1, b1, w2, b2, gw, gb, lw, lb, gamma, beta,
                       mask, out);
}

// Round 2
// 462.650 us; speedup vs baseline: 2.0214x; 2.0214x over previous
//
#include <hip/hip_runtime.h>
#include <math.h>

#define NB 16384
#define NF 32
#define ND 64
#define NIN 2048

typedef __attribute__((ext_vector_type(8))) short fragA;   // 8 bf16
typedef __attribute__((ext_vector_type(4))) float fragC;   // 4 fp32

#define MFMA(a, b, c) __builtin_amdgcn_mfma_f32_16x16x32_bf16((a), (b), (c), 0, 0, 0)

__device__ __forceinline__ short f2bf(float f) {
    union { float f; unsigned u; } v; v.f = f;
    unsigned r = (v.u + 0x7fffu + ((v.u >> 16) & 1u)) >> 16;  // RNE
    return (short)r;
}
__device__ __forceinline__ float bf2f(short s) {
    union { unsigned u; float f; } v;
    v.u = ((unsigned)(unsigned short)s) << 16;
    return v.f;
}
// read 8 consecutive fp32 from 16B-aligned LDS, convert to bf16 A/B fragment
__device__ __forceinline__ fragA cvt8(const float* p) {
    float4 a = *(const float4*)p;
    float4 b = *(const float4*)(p + 4);
    fragA r;
    r[0] = f2bf(a.x); r[1] = f2bf(a.y); r[2] = f2bf(a.z); r[3] = f2bf(a.w);
    r[4] = f2bf(b.x); r[5] = f2bf(b.y); r[6] = f2bf(b.z); r[7] = f2bf(b.w);
    return r;
}

// ---------------------------------------------------------------------------
// Prologue: convert weights to bf16 in B-fragment-linear layout in d_ws.
//   frag index F: [0,65536): grn weights  w1,w2,gw,lw
//       F = ((mat*32+f)*512) + nt*128 + s*64 + lane ; elem j=0..7
//       covers B[k][n], k = s*32 + (lane>>4)*8 + j, n = nt*16 + (lane&15)
//   [65536, 90112): mask weights mw1 (cols 0..63) ++ mlw (cols 64..95)
//       F-65536 = f*768 + nt*128 + s*64 + lane, k global = f*64 + klocal
// ---------------------------------------------------------------------------
__global__ __launch_bounds__(256) void prep_kernel(
    const float* __restrict__ w1, const float* __restrict__ w2,
    const float* __restrict__ gw, const float* __restrict__ lw,
    const float* __restrict__ mw1, const float* __restrict__ mlw,
    short* __restrict__ wsout)
{
    int F = blockIdx.x * 256 + threadIdx.x;   // grid sized exactly 90112/256
    fragA o;
    if (F < 65536) {
        int mat = F >> 14;
        int f   = (F >> 9) & 31;
        int nt  = (F >> 7) & 3;
        int s   = (F >> 6) & 1;
        int l   = F & 63;
        const float* src = (mat == 0 ? w1 : mat == 1 ? w2 : mat == 2 ? gw : lw)
                           + (size_t)f * 4096;
        int n  = nt * 16 + (l & 15);
        int k0 = s * 32 + ((l >> 4) << 3);
#pragma unroll
        for (int j = 0; j < 8; ++j) o[j] = f2bf(src[(k0 + j) * 64 + n]);
    } else {
        int G  = F - 65536;
        int f  = G / 768;
        int r  = G - f * 768;
        int nt = r >> 7;
        int s  = (r >> 6) & 1;
        int l  = r & 63;
        int n  = nt * 16 + (l & 15);
        int k0 = f * 64 + s * 32 + ((l >> 4) << 3);
        if (n < 64) {
#pragma unroll
            for (int j = 0; j < 8; ++j) o[j] = f2bf(mw1[(size_t)(k0 + j) * 64 + n]);
        } else {
#pragma unroll
            for (int j = 0; j < 8; ++j) o[j] = f2bf(mlw[(size_t)(k0 + j) * 32 + (n - 64)]);
        }
    }
    ((fragA*)wsout)[F] = o;
}

// ---------------------------------------------------------------------------
// Kernel 1: mask branch.  64 rows/block, 4 waves, wave = 16 rows.
// Big GEMM [64 x 96 x 2048] via MFMA (6 n-tiles); small GEMMs scalar fp32.
// Entire per-wave pipeline is wave-local; single initial __syncthreads.
// ---------------------------------------------------------------------------
__global__ __launch_bounds__(256) void mask_kernel(
    const float* __restrict__ x, const short* __restrict__ mwfrag,
    const float* __restrict__ mb1, const float* __restrict__ mw2,
    const float* __restrict__ mb2, const float* __restrict__ mlb,
    const float* __restrict__ mgw, const float* __restrict__ mgb,
    const float* __restrict__ mlw2, const float* __restrict__ mlb2,
    const float* __restrict__ mgamma, const float* __restrict__ mbeta,
    float* __restrict__ mask_out)
{
    __shared__ float xS[4][16 * 68];     // x chunk (fp32); reused as h after K-loop
    __shared__ float resS[4][16 * 36];
    __shared__ float h2S[4][16 * 36];
    __shared__ float mw2S[64 * 36];
    __shared__ float mgwS[32 * 36];
    __shared__ float mlw2S[32 * 36];
    __shared__ float vmb1[64];
    __shared__ float vsm[6][32];         // mb2, mlb, mgb, mlb2, mgamma, mbeta

    const int tid = threadIdx.x;
    const int w = tid >> 6, l = tid & 63;
    const int row0 = blockIdx.x * 64;
    const int m = l & 15, q = l >> 4;

    for (int i = tid; i < 2048; i += 256) mw2S[(i >> 5) * 36 + (i & 31)] = mw2[i];
    for (int i = tid; i < 1024; i += 256) {
        mgwS[(i >> 5) * 36 + (i & 31)] = mgw[i];
        mlw2S[(i >> 5) * 36 + (i & 31)] = mlw2[i];
    }
    if (tid < 64) vmb1[tid] = mb1[tid];
    if (tid < 32) {
        vsm[0][tid] = mb2[tid];  vsm[1][tid] = mlb[tid];
        vsm[2][tid] = mgb[tid];  vsm[3][tid] = mlb2[tid];
        vsm[4][tid] = mgamma[tid]; vsm[5][tid] = mbeta[tid];
    }
    __syncthreads();

    float* xW = xS[w];
    float* resW = resS[w];
    float* h2W = h2S[w];
    const fragA* wf = (const fragA*)mwfrag;

    fragC acc[6];
#pragma unroll
    for (int nt = 0; nt < 6; ++nt) acc[nt] = (fragC){0.f, 0.f, 0.f, 0.f};

    const int sr = l >> 2, sc = (l & 3) * 16;
    const float* xg = x + (size_t)(row0 + w * 16 + sr) * NIN + sc;

    for (int f = 0; f < NF; ++f) {
        // stage x chunk (wave-local rows)
        const float4* gp = (const float4*)(xg + f * ND);
        float4 v0 = gp[0], v1 = gp[1], v2 = gp[2], v3 = gp[3];
        float4* d = (float4*)(xW + sr * 68 + sc);
        d[0] = v0; d[1] = v1; d[2] = v2; d[3] = v3;

        const float* ap = xW + m * 68 + q * 8;
        fragA a0 = cvt8(ap), a1 = cvt8(ap + 32);
        const size_t fb = (size_t)f * 768 + l;
#pragma unroll
        for (int nt = 0; nt < 6; ++nt) {
            acc[nt] = MFMA(a0, wf[fb + nt * 128], acc[nt]);
            acc[nt] = MFMA(a1, wf[fb + nt * 128 + 64], acc[nt]);
        }
    }

    // h = elu(acc[0..3] + mb1) -> xW ;  res = acc[4..5] + mlb -> resW
#pragma unroll
    for (int nt = 0; nt < 4; ++nt) {
        int col = nt * 16 + m;
        float bv = vmb1[col];
#pragma unroll
        for (int rg = 0; rg < 4; ++rg) {
            float v = acc[nt][rg] + bv;
            xW[(q * 4 + rg) * 68 + col] = v > 0.f ? v : expm1f(v);
        }
    }
#pragma unroll
    for (int nt = 4; nt < 6; ++nt) {
        int col = (nt - 4) * 16 + m;
        float bv = vsm[1][col];
#pragma unroll
        for (int rg = 0; rg < 4; ++rg)
            resW[(q * 4 + rg) * 36 + col] = acc[nt][rg] + bv;
    }

    const int r2 = l >> 2, c0 = (l & 3) * 8;
    // h2 = h @ mw2 + mb2   (lane: row r2, cols c0..c0+7)
    {
        float h2v[8];
#pragma unroll
        for (int i = 0; i < 8; ++i) h2v[i] = vsm[0][c0 + i];
        for (int k = 0; k < 64; ++k) {
            float hv = xW[r2 * 68 + k];
            float4 w0 = *(const float4*)(mw2S + k * 36 + c0);
            float4 w1 = *(const float4*)(mw2S + k * 36 + c0 + 4);
            h2v[0] += hv * w0.x; h2v[1] += hv * w0.y; h2v[2] += hv * w0.z; h2v[3] += hv * w0.w;
            h2v[4] += hv * w1.x; h2v[5] += hv * w1.y; h2v[6] += hv * w1.z; h2v[7] += hv * w1.w;
        }
        float4* hd = (float4*)(h2W + r2 * 36 + c0);
        hd[0] = (float4){h2v[0], h2v[1], h2v[2], h2v[3]};
        hd[1] = (float4){h2v[4], h2v[5], h2v[6], h2v[7]};
    }
    // gate/lin (32x32), pre, LN over F=32, softmax, store
    {
        float gv[8], lv[8];
#pragma unroll
        for (int i = 0; i < 8; ++i) { gv[i] = vsm[2][c0 + i]; lv[i] = vsm[3][c0 + i]; }
        for (int k = 0; k < 32; ++k) {
            float hv = h2W[r2 * 36 + k];
            float4 g0 = *(const float4*)(mgwS + k * 36 + c0);
            float4 g1 = *(const float4*)(mgwS + k * 36 + c0 + 4);
            float4 l0 = *(const float4*)(mlw2S + k * 36 + c0);
            float4 l1 = *(const float4*)(mlw2S + k * 36 + c0 + 4);
            gv[0] += hv * g0.x; gv[1] += hv * g0.y; gv[2] += hv * g0.z; gv[3] += hv * g0.w;
            gv[4] += hv * g1.x; gv[5] += hv * g1.y; gv[6] += hv * g1.z; gv[7] += hv * g1.w;
            lv[0] += hv * l0.x; lv[1] += hv * l0.y; lv[2] += hv * l0.z; lv[3] += hv * l0.w;
            lv[4] += hv * l1.x; lv[5] += hv * l1.y; lv[6] += hv * l1.z; lv[7] += hv * l1.w;
        }
        float pre[8];
#pragma unroll
        for (int i = 0; i < 8; ++i) {
            float sg = 1.f / (1.f + expf(-gv[i]));
            pre[i] = lv[i] * sg + resW[r2 * 36 + c0 + i];
        }
        float s1 = 0.f;
#pragma unroll
        for (int i = 0; i < 8; ++i) s1 += pre[i];
        s1 += __shfl_xor(s1, 1); s1 += __shfl_xor(s1, 2);
        float mean = s1 * (1.f / 32.f);
        float s2 = 0.f;
#pragma unroll
        for (int i = 0; i < 8; ++i) { float dd = pre[i] - mean; s2 += dd * dd; }
        s2 += __shfl_xor(s2, 1); s2 += __shfl_xor(s2, 2);
        float inv = rsqrtf(s2 * (1.f / 32.f) + 1e-5f);
        float ln[8]; float mx = -3.4e38f;
#pragma unroll
        for (int i = 0; i < 8; ++i) {
            ln[i] = (pre[i] - mean) * inv * vsm[4][c0 + i] + vsm[5][c0 + i];
            mx = fmaxf(mx, ln[i]);
        }
        mx = fmaxf(mx, __shfl_xor(mx, 1));
        mx = fmaxf(mx, __shfl_xor(mx, 2));
        float ssum = 0.f;
#pragma unroll
        for (int i = 0; i < 8; ++i) { ln[i] = expf(ln[i] - mx); ssum += ln[i]; }
        ssum += __shfl_xor(ssum, 1); ssum += __shfl_xor(ssum, 2);
        float rs = 1.f / ssum;
        float* mo = mask_out + (size_t)(row0 + w * 16 + r2) * 32 + c0;
        *(float4*)mo       = (float4){ln[0] * rs, ln[1] * rs, ln[2] * rs, ln[3] * rs};
        *(float4*)(mo + 4) = (float4){ln[4] * rs, ln[5] * rs, ln[6] * rs, ln[7] * rs};
    }
}

// ---------------------------------------------------------------------------
// Kernel 2: per-feature GRN chain, all 4 GEMMs on MFMA, wave-local (no
// __syncthreads in the f-loop).  Wave = 16 rows; intermediates round-trip
// through wave-private padded fp32 LDS (write C-layout, read A-frag b128+cvt).
// ---------------------------------------------------------------------------
__global__ __launch_bounds__(256) void grn_kernel(
    const float* __restrict__ x, const short* __restrict__ wfrag,
    const float* __restrict__ b1, const float* __restrict__ b2,
    const float* __restrict__ gb, const float* __restrict__ lb,
    const float* __restrict__ gamma, const float* __restrict__ beta,
    const float* __restrict__ mask, float* __restrict__ out)
{
    __shared__ float xS[4][16 * 68];   // x chunk fp32 (GEMM1 A + residual)
    __shared__ float hS[4][16 * 68];   // h1, then h2 (wave-local reuse)
    __shared__ short bb[6][2048];      // b1,b2,gb,lb,gamma,beta as bf16

    const int tid = threadIdx.x;
    const int w = tid >> 6, l = tid & 63;
    const int row0 = blockIdx.x * 64;
    const int m = l & 15, q = l >> 4;

    {
        const float* bp[6] = { b1, b2, gb, lb, gamma, beta };
#pragma unroll
        for (int j = 0; j < 6; ++j)
            for (int i = tid; i < 2048; i += 256) bb[j][i] = f2bf(bp[j][i]);
    }
    __syncthreads();

    float* xW = xS[w];
    float* hW = hS[w];
    const fragA* wf = (const fragA*)wfrag;

    fragC oac[4];
#pragma unroll
    for (int nt = 0; nt < 4; ++nt) oac[nt] = (fragC){0.f, 0.f, 0.f, 0.f};

    const int sr = l >> 2, sc = (l & 3) * 16;
    const float* xg = x + (size_t)(row0 + w * 16 + sr) * NIN + sc;

    for (int f = 0; f < NF; ++f) {
        // stage x chunk (fp32, wave-local rows)
        {
            const float4* gp = (const float4*)(xg + f * ND);
            float4 v0 = gp[0], v1 = gp[1], v2 = gp[2], v3 = gp[3];
            float4* d = (float4*)(xW + sr * 68 + sc);
            d[0] = v0; d[1] = v1; d[2] = v2; d[3] = v3;
        }
        // GEMM1: h1 = elu(x @ w1 + b1) -> hW
        {
            const float* ap = xW + m * 68 + q * 8;
            fragA a0 = cvt8(ap), a1 = cvt8(ap + 32);
            const size_t base = ((size_t)(0 * NF + f)) * 512 + l;
#pragma unroll
            for (int nt = 0; nt < 4; ++nt) {
                fragC c = {0.f, 0.f, 0.f, 0.f};
                c = MFMA(a0, wf[base + (nt * 2) * 64], c);
                c = MFMA(a1, wf[base + (nt * 2 + 1) * 64], c);
                int col = nt * 16 + m;
                float bv = bf2f(bb[0][f * 64 + col]);
#pragma unroll
                for (int rg = 0; rg < 4; ++rg) {
                    float v = c[rg] + bv;
                    hW[(q * 4 + rg) * 68 + col] = v > 0.f ? v : expm1f(v);
                }
            }
        }
        // GEMM2: h2 = h1 @ w2 + b2 -> hW (A-frags fully read before writes)
        {
            const float* ap = hW + m * 68 + q * 8;
            fragA a0 = cvt8(ap), a1 = cvt8(ap + 32);
            const size_t base = ((size_t)(1 * NF + f)) * 512 + l;
            fragC cc[4];
#pragma unroll
            for (int nt = 0; nt < 4; ++nt) {
                fragC c = {0.f, 0.f, 0.f, 0.f};
                c = MFMA(a0, wf[base + (nt * 2) * 64], c);
                c = MFMA(a1, wf[base + (nt * 2 + 1) * 64], c);
                cc[nt] = c;
            }
#pragma unroll
            for (int nt = 0; nt < 4; ++nt) {
                int col = nt * 16 + m;
                float bv = bf2f(bb[1][f * 64 + col]);
#pragma unroll
                for (int rg = 0; rg < 4; ++rg)
                    hW[(q * 4 + rg) * 68 + col] = cc[nt][rg] + bv;
            }
        }
        // GEMM3+4: gate & lin from h2; epilogue with LN over D and mask-acc
        {
            const float* ap = hW + m * 68 + q * 8;
            fragA a0 = cvt8(ap), a1 = cvt8(ap + 32);
            const size_t baseg = ((size_t)(2 * NF + f)) * 512 + l;
            const size_t basel = ((size_t)(3 * NF + f)) * 512 + l;
            fragC ga[4], la[4];
#pragma unroll
            for (int nt = 0; nt < 4; ++nt) {
                fragC g = {0.f, 0.f, 0.f, 0.f}, li = {0.f, 0.f, 0.f, 0.f};
                g  = MFMA(a0, wf[baseg + (nt * 2) * 64], g);
                g  = MFMA(a1, wf[baseg + (nt * 2 + 1) * 64], g);
                li = MFMA(a0, wf[basel + (nt * 2) * 64], li);
                li = MFMA(a1, wf[basel + (nt * 2 + 1) * 64], li);
                ga[nt] = g; la[nt] = li;
            }
#pragma unroll
            for (int rg = 0; rg < 4; ++rg) {
                float val[4];
#pragma unroll
                for (int nt = 0; nt < 4; ++nt) {
                    int col = nt * 16 + m;
                    float gg = ga[nt][rg] + bf2f(bb[2][f * 64 + col]);
                    float ll = la[nt][rg] + bf2f(bb[3][f * 64 + col]);
                    float sg = 1.f / (1.f + expf(-gg));
                    val[nt] = ll * sg + xW[(q * 4 + rg) * 68 + col];
                }
                float s1 = val[0] + val[1] + val[2] + val[3];
                s1 += __shfl_xor(s1, 1); s1 += __shfl_xor(s1, 2);
                s1 += __shfl_xor(s1, 4); s1 += __shfl_xor(s1, 8);
                float mean = s1 * (1.f / 64.f);
                float s2 = 0.f;
#pragma unroll
                for (int nt = 0; nt < 4; ++nt) { float dd = val[nt] - mean; s2 += dd * dd; }
                s2 += __shfl_xor(s2, 1); s2 += __shfl_xor(s2, 2);
                s2 += __shfl_xor(s2, 4); s2 += __shfl_xor(s2, 8);
                float inv = rsqrtf(s2 * (1.f / 64.f) + 1e-5f);
                float mk = mask[(size_t)(row0 + w * 16 + q * 4 + rg) * 32 + f];
#pragma unroll
                for (int nt = 0; nt < 4; ++nt) {
                    int col = nt * 16 + m;
                    float vec = (val[nt] - mean) * inv * bf2f(bb[4][f * 64 + col])
                                + bf2f(bb[5][f * 64 + col]);
                    oac[nt][rg] += mk * vec;
                }
            }
        }
    }

#pragma unroll
    for (int nt = 0; nt < 4; ++nt)
#pragma unroll
        for (int rg = 0; rg < 4; ++rg)
            out[(size_t)(row0 + w * 16 + q * 4 + rg) * 64 + nt * 16 + m] = oac[nt][rg];
}

// ---------------------------------------------------------------------------
extern "C" void kernel_launch(void* const* d_in, const int* in_sizes, int n_in,
                              void* d_out, int out_size, void* d_ws, size_t ws_size,
                              hipStream_t stream) {
    const float* x      = (const float*)d_in[0];
    const float* mw1    = (const float*)d_in[1];
    const float* mb1    = (const float*)d_in[2];
    const float* mw2    = (const float*)d_in[3];
    const float* mb2    = (const float*)d_in[4];
    const float* mlw    = (const float*)d_in[5];
    const float* mlb    = (const float*)d_in[6];
    const float* mgw    = (const float*)d_in[7];
    const float* mgb    = (const float*)d_in[8];
    const float* mlw2   = (const float*)d_in[9];
    const float* mlb2   = (const float*)d_in[10];
    const float* mgamma = (const float*)d_in[11];
    const float* mbeta  = (const float*)d_in[12];
    const float* w1     = (const float*)d_in[13];
    const float* b1     = (const float*)d_in[14];
    const float* w2     = (const float*)d_in[15];
    const float* b2     = (const float*)d_in[16];
    const float* gw     = (const float*)d_in[17];
    const float* gb     = (const float*)d_in[18];
    const float* lw     = (const float*)d_in[19];
    const float* lb     = (const float*)d_in[20];
    const float* gamma  = (const float*)d_in[21];
    const float* beta   = (const float*)d_in[22];

    float* out  = (float*)d_out;                 // [B,64]
    float* mask = out + (size_t)NB * 64;         // [B,32] (second output)

    short* wfrag  = (short*)d_ws;                // 65536 frags (grn weights)
    short* mwfrag = wfrag + (size_t)65536 * 8;   // 24576 frags (mask weights)

    hipLaunchKernelGGL(prep_kernel, dim3(352), dim3(256), 0, stream,
                       w1, w2, gw, lw, mw1, mlw, wfrag);
    hipLaunchKernelGGL(mask_kernel, dim3(NB / 64), dim3(256), 0, stream,
                       x, mwfrag, mb1, mw2, mb2, mlb, mgw, mgb, mlw2, mlb2,
                       mgamma, mbeta, mask);
    hipLaunchKernelGGL(grn_kernel, dim3(NB / 64), dim3(256), 0, stream,
                       x, wfrag, b1, b2, gb, lb, gamma, beta, mask, out);
}

// Round 3
// 363.298 us; speedup vs baseline: 2.5743x; 1.2735x over previous
//
#include <hip/hip_runtime.h>
#include <math.h>

#define NB 16384
#define NF 32
#define ND 64
#define NIN 2048

typedef __attribute__((ext_vector_type(8))) short fragA;   // 8 bf16
typedef __attribute__((ext_vector_type(4))) float fragC;   // 4 fp32

#define MFMA(a, b, c) __builtin_amdgcn_mfma_f32_16x16x32_bf16((a), (b), (c), 0, 0, 0)

__device__ __forceinline__ short f2bf(float f) {
    union { float f; unsigned u; } v; v.f = f;
    return (short)((v.u + 0x7fffu + ((v.u >> 16) & 1u)) >> 16);  // RNE
}
// read 8 consecutive fp32 (global or LDS), convert to bf16 fragment
__device__ __forceinline__ fragA cvt8(const float* p) {
    float4 a = *(const float4*)p;
    float4 b = *(const float4*)(p + 4);
    fragA r;
    r[0] = f2bf(a.x); r[1] = f2bf(a.y); r[2] = f2bf(a.z); r[3] = f2bf(a.w);
    r[4] = f2bf(b.x); r[5] = f2bf(b.y); r[6] = f2bf(b.z); r[7] = f2bf(b.w);
    return r;
}

// ---------------------------------------------------------------------------
// Prologue: weights -> bf16 B-fragment-linear layout in d_ws (same as R2).
// ---------------------------------------------------------------------------
__global__ __launch_bounds__(256) void prep_kernel(
    const float* __restrict__ w1, const float* __restrict__ w2,
    const float* __restrict__ gw, const float* __restrict__ lw,
    const float* __restrict__ mw1, const float* __restrict__ mlw,
    short* __restrict__ wsout)
{
    int F = blockIdx.x * 256 + threadIdx.x;
    fragA o;
    if (F < 65536) {
        int mat = F >> 14;
        int f   = (F >> 9) & 31;
        int nt  = (F >> 7) & 3;
        int s   = (F >> 6) & 1;
        int l   = F & 63;
        const float* src = (mat == 0 ? w1 : mat == 1 ? w2 : mat == 2 ? gw : lw)
                           + (size_t)f * 4096;
        int n  = nt * 16 + (l & 15);
        int k0 = s * 32 + ((l >> 4) << 3);
#pragma unroll
        for (int j = 0; j < 8; ++j) o[j] = f2bf(src[(k0 + j) * 64 + n]);
    } else {
        int G  = F - 65536;
        int f  = G / 768;
        int r  = G - f * 768;
        int nt = r >> 7;
        int s  = (r >> 6) & 1;
        int l  = r & 63;
        int n  = nt * 16 + (l & 15);
        int k0 = f * 64 + s * 32 + ((l >> 4) << 3);
        if (n < 64) {
#pragma unroll
            for (int j = 0; j < 8; ++j) o[j] = f2bf(mw1[(size_t)(k0 + j) * 64 + n]);
        } else {
#pragma unroll
            for (int j = 0; j < 8; ++j) o[j] = f2bf(mlw[(size_t)(k0 + j) * 32 + (n - 64)]);
        }
    }
    ((fragA*)wsout)[F] = o;
}

// ---------------------------------------------------------------------------
// Fused kernel: block = 16 rows, 4 waves; waves split the f-axis (8 each).
// Phase 1: mask branch (MFMA partials -> LDS reduce -> small GEMMs -> LN ->
//          softmax -> maskS in LDS + global store).
// Phase 2: per-feature GRN chain per wave (wave-local LDS h), mask-weighted
//          partial sums, cross-wave LDS reduction, store.
// LDS 51.97 KB -> 3 blocks/CU (3 waves/SIMD).
// ---------------------------------------------------------------------------
__global__ __launch_bounds__(256, 3) void fused_kernel(
    const float* __restrict__ x,
    const short* __restrict__ wfrag, const short* __restrict__ mwfrag,
    const float* __restrict__ mb1, const float* __restrict__ mw2,
    const float* __restrict__ mb2, const float* __restrict__ mlb,
    const float* __restrict__ mgw, const float* __restrict__ mgb,
    const float* __restrict__ mlw2, const float* __restrict__ mlb2,
    const float* __restrict__ mgamma, const float* __restrict__ mbeta,
    const float* __restrict__ b1, const float* __restrict__ b2,
    const float* __restrict__ gb, const float* __restrict__ lb,
    const float* __restrict__ gamma, const float* __restrict__ beta,
    float* __restrict__ mask_out, float* __restrict__ out)
{
    __shared__ float smem[12992];           // 51,968 B
    float* redS  = smem;                    // phase1 partials: 4 x 16x97
    float* wmw2  = smem + 6208;             // 64x36
    float* wmgw  = smem + 8512;             // 32x36
    float* wmlw2 = smem + 9664;             // 32x36
    float* hS1   = smem + 10816;            // 16x68
    float* resS  = smem + 11904;            // 16x36
    float* maskS = smem + 12480;            // 16x32 (persists into phase 2)
    float* h2S   = smem;                    // stage B/C alias (576 floats)
    float* preS  = smem + 640;              // stage C/D alias (576 floats)

    const int tid = threadIdx.x;
    const int w = tid >> 6, l = tid & 63;
    const int row0 = blockIdx.x * 16;
    const int m = l & 15, q = l >> 4;

    const fragA* wf  = (const fragA*)wfrag;
    const fragA* mwf = (const fragA*)mwfrag;

    // ------------------------- Phase 1: mask -------------------------
    fragC acc[6];
#pragma unroll
    for (int nt = 0; nt < 6; ++nt) acc[nt] = (fragC){0.f, 0.f, 0.f, 0.f};

    const float* xpm = x + (size_t)(row0 + m) * NIN + q * 8;
    for (int fi = 0; fi < 8; ++fi) {
        int f = w * 8 + fi;
        const float* xp = xpm + f * ND;
        fragA a0 = cvt8(xp), a1 = cvt8(xp + 32);
        const size_t fb = (size_t)f * 768 + l;
#pragma unroll
        for (int nt = 0; nt < 6; ++nt) {
            acc[nt] = MFMA(a0, mwf[fb + nt * 128], acc[nt]);
            acc[nt] = MFMA(a1, mwf[fb + nt * 128 + 64], acc[nt]);
        }
    }
    // write per-wave partials (16x96, stride 97)
#pragma unroll
    for (int nt = 0; nt < 6; ++nt)
#pragma unroll
        for (int rg = 0; rg < 4; ++rg)
            redS[w * 1552 + (q * 4 + rg) * 97 + nt * 16 + m] = acc[nt][rg];
    // cooperative small-weight staging
    for (int i = tid; i < 2048; i += 256) wmw2[(i >> 5) * 36 + (i & 31)] = mw2[i];
    for (int i = tid; i < 1024; i += 256) {
        wmgw[(i >> 5) * 36 + (i & 31)]  = mgw[i];
        wmlw2[(i >> 5) * 36 + (i & 31)] = mlw2[i];
    }
    __syncthreads();

    // stage A: reduce partials; h = elu(.+mb1), res = .+mlb
    {
        int r = tid & 15, cb = tid >> 4;
#pragma unroll
        for (int i = 0; i < 6; ++i) {
            int c = cb + i * 16;
            float s = redS[r * 97 + c] + redS[1552 + r * 97 + c]
                    + redS[3104 + r * 97 + c] + redS[4656 + r * 97 + c];
            if (c < 64) {
                float v = s + mb1[c];
                hS1[r * 68 + c] = v > 0.f ? v : expm1f(v);
            } else {
                resS[r * 36 + (c - 64)] = s + mlb[c - 64];
            }
        }
    }
    __syncthreads();

    // stage B: h2 = h @ mw2 + mb2
    {
        int r = tid & 15, c = tid >> 4;
        float h0 = mb2[c], h1 = mb2[c + 16];
        for (int k = 0; k < 64; ++k) {
            float hv = hS1[r * 68 + k];
            h0 += hv * wmw2[k * 36 + c];
            h1 += hv * wmw2[k * 36 + c + 16];
        }
        h2S[r * 36 + c] = h0;
        h2S[r * 36 + c + 16] = h1;
    }
    __syncthreads();

    // stage C: pre = sigmoid(h2@mgw+mgb) * (h2@mlw2+mlb2) + res
    {
        int r = tid & 15, c = tid >> 4;
        float g0 = mgb[c], g1 = mgb[c + 16], l0 = mlb2[c], l1 = mlb2[c + 16];
        for (int k = 0; k < 32; ++k) {
            float hv = h2S[r * 36 + k];
            g0 += hv * wmgw[k * 36 + c];
            g1 += hv * wmgw[k * 36 + c + 16];
            l0 += hv * wmlw2[k * 36 + c];
            l1 += hv * wmlw2[k * 36 + c + 16];
        }
        preS[r * 36 + c]      = l0 / (1.f + expf(-g0)) + resS[r * 36 + c];
        preS[r * 36 + c + 16] = l1 / (1.f + expf(-g1)) + resS[r * 36 + c + 16];
    }
    __syncthreads();

    // stage D: LN(F=32) + softmax (wave 0), store mask to LDS + global
    if (w == 0) {
        int r2 = l >> 2, c0 = (l & 3) * 8;
        float pre[8];
#pragma unroll
        for (int i = 0; i < 8; ++i) pre[i] = preS[r2 * 36 + c0 + i];
        float s1 = 0.f;
#pragma unroll
        for (int i = 0; i < 8; ++i) s1 += pre[i];
        s1 += __shfl_xor(s1, 1); s1 += __shfl_xor(s1, 2);
        float mean = s1 * (1.f / 32.f);
        float s2 = 0.f;
#pragma unroll
        for (int i = 0; i < 8; ++i) { float d = pre[i] - mean; s2 += d * d; }
        s2 += __shfl_xor(s2, 1); s2 += __shfl_xor(s2, 2);
        float inv = rsqrtf(s2 * (1.f / 32.f) + 1e-5f);
        float ln[8]; float mx = -3.4e38f;
#pragma unroll
        for (int i = 0; i < 8; ++i) {
            ln[i] = (pre[i] - mean) * inv * mgamma[c0 + i] + mbeta[c0 + i];
            mx = fmaxf(mx, ln[i]);
        }
        mx = fmaxf(mx, __shfl_xor(mx, 1));
        mx = fmaxf(mx, __shfl_xor(mx, 2));
        float ssum = 0.f;
#pragma unroll
        for (int i = 0; i < 8; ++i) { ln[i] = expf(ln[i] - mx); ssum += ln[i]; }
        ssum += __shfl_xor(ssum, 1); ssum += __shfl_xor(ssum, 2);
        float rs = 1.f / ssum;
        float* mo = mask_out + (size_t)(row0 + r2) * 32 + c0;
        *(float4*)mo       = (float4){ln[0] * rs, ln[1] * rs, ln[2] * rs, ln[3] * rs};
        *(float4*)(mo + 4) = (float4){ln[4] * rs, ln[5] * rs, ln[6] * rs, ln[7] * rs};
#pragma unroll
        for (int i = 0; i < 8; ++i) maskS[r2 * 32 + c0 + i] = ln[i] * rs;
    }
    __syncthreads();

    // ------------------------- Phase 2: GRNs -------------------------
    float* hW   = smem + w * 1088;          // per-wave 16x68 (aliases redS)
    float* outS = smem + 4352;              // 4 x 16x68 partial outputs

    fragC oac[4];
#pragma unroll
    for (int nt = 0; nt < 4; ++nt) oac[nt] = (fragC){0.f, 0.f, 0.f, 0.f};

    for (int fi = 0; fi < 8; ++fi) {
        int f = w * 8 + fi;
        // prefetch residual, biases, mask (hidden behind MFMA work)
        float xres[4][4];
#pragma unroll
        for (int rg = 0; rg < 4; ++rg)
#pragma unroll
            for (int nt = 0; nt < 4; ++nt)
                xres[rg][nt] = x[(size_t)(row0 + q * 4 + rg) * NIN + f * ND + nt * 16 + m];
        float b1v[4], b2v[4], gbv[4], lbv[4], gmv[4], btv[4];
#pragma unroll
        for (int nt = 0; nt < 4; ++nt) {
            int c = f * 64 + nt * 16 + m;
            b1v[nt] = b1[c]; b2v[nt] = b2[c]; gbv[nt] = gb[c];
            lbv[nt] = lb[c]; gmv[nt] = gamma[c]; btv[nt] = beta[c];
        }
        float mk[4];
#pragma unroll
        for (int rg = 0; rg < 4; ++rg) mk[rg] = maskS[(q * 4 + rg) * 32 + f];

        // GEMM1: h1 = elu(x @ w1 + b1) -> hW (A direct from global)
        {
            const float* xp = xpm + f * ND;
            fragA a0 = cvt8(xp), a1 = cvt8(xp + 32);
            const size_t base = (size_t)f * 512 + l;
#pragma unroll
            for (int nt = 0; nt < 4; ++nt) {
                fragC c = {0.f, 0.f, 0.f, 0.f};
                c = MFMA(a0, wf[base + nt * 128], c);
                c = MFMA(a1, wf[base + nt * 128 + 64], c);
                int col = nt * 16 + m;
#pragma unroll
                for (int rg = 0; rg < 4; ++rg) {
                    float v = c[rg] + b1v[nt];
                    hW[(q * 4 + rg) * 68 + col] = v > 0.f ? v : expm1f(v);
                }
            }
        }
        // GEMM2: h2 = h1 @ w2 + b2 -> hW
        {
            const float* ap = hW + m * 68 + q * 8;
            fragA a0 = cvt8(ap), a1 = cvt8(ap + 32);
            const size_t base = ((size_t)(NF + f)) * 512 + l;
            fragC cc[4];
#pragma unroll
            for (int nt = 0; nt < 4; ++nt) {
                fragC c = {0.f, 0.f, 0.f, 0.f};
                c = MFMA(a0, wf[base + nt * 128], c);
                c = MFMA(a1, wf[base + nt * 128 + 64], c);
                cc[nt] = c;
            }
#pragma unroll
            for (int nt = 0; nt < 4; ++nt) {
                int col = nt * 16 + m;
#pragma unroll
                for (int rg = 0; rg < 4; ++rg)
                    hW[(q * 4 + rg) * 68 + col] = cc[nt][rg] + b2v[nt];
            }
        }
        // GEMM3+4 + epilogue
        {
            const float* ap = hW + m * 68 + q * 8;
            fragA a0 = cvt8(ap), a1 = cvt8(ap + 32);
            const size_t baseg = ((size_t)(2 * NF + f)) * 512 + l;
            const size_t basel = ((size_t)(3 * NF + f)) * 512 + l;
            fragC ga[4], la[4];
#pragma unroll
            for (int nt = 0; nt < 4; ++nt) {
                fragC g = {0.f, 0.f, 0.f, 0.f}, li = {0.f, 0.f, 0.f, 0.f};
                g  = MFMA(a0, wf[baseg + nt * 128], g);
                g  = MFMA(a1, wf[baseg + nt * 128 + 64], g);
                li = MFMA(a0, wf[basel + nt * 128], li);
                li = MFMA(a1, wf[basel + nt * 128 + 64], li);
                ga[nt] = g; la[nt] = li;
            }
#pragma unroll
            for (int rg = 0; rg < 4; ++rg) {
                float val[4];
#pragma unroll
                for (int nt = 0; nt < 4; ++nt) {
                    float gg = ga[nt][rg] + gbv[nt];
                    float ll = la[nt][rg] + lbv[nt];
                    val[nt] = ll / (1.f + expf(-gg)) + xres[rg][nt];
                }
                float s1 = val[0] + val[1] + val[2] + val[3];
                s1 += __shfl_xor(s1, 1); s1 += __shfl_xor(s1, 2);
                s1 += __shfl_xor(s1, 4); s1 += __shfl_xor(s1, 8);
                float mean = s1 * (1.f / 64.f);
                float s2 = 0.f;
#pragma unroll
                for (int nt = 0; nt < 4; ++nt) { float d = val[nt] - mean; s2 += d * d; }
                s2 += __shfl_xor(s2, 1); s2 += __shfl_xor(s2, 2);
                s2 += __shfl_xor(s2, 4); s2 += __shfl_xor(s2, 8);
                float inv = rsqrtf(s2 * (1.f / 64.f) + 1e-5f);
#pragma unroll
                for (int nt = 0; nt < 4; ++nt) {
                    float vec = (val[nt] - mean) * inv * gmv[nt] + btv[nt];
                    oac[nt][rg] += mk[rg] * vec;
                }
            }
        }
    }

    // cross-wave output reduction
#pragma unroll
    for (int nt = 0; nt < 4; ++nt)
#pragma unroll
        for (int rg = 0; rg < 4; ++rg)
            outS[w * 1088 + (q * 4 + rg) * 68 + nt * 16 + m] = oac[nt][rg];
    __syncthreads();
    {
        int t4 = tid * 4;
        int r = t4 >> 6, c = t4 & 63;
        float v[4];
#pragma unroll
        for (int j = 0; j < 4; ++j) {
            v[j] = outS[r * 68 + c + j] + outS[1088 + r * 68 + c + j]
                 + outS[2176 + r * 68 + c + j] + outS[3264 + r * 68 + c + j];
        }
        *(float4*)(out + (size_t)(row0 + r) * 64 + c) = (float4){v[0], v[1], v[2], v[3]};
    }
}

// ---------------------------------------------------------------------------
extern "C" void kernel_launch(void* const* d_in, const int* in_sizes, int n_in,
                              void* d_out, int out_size, void* d_ws, size_t ws_size,
                              hipStream_t stream) {
    const float* x      = (const float*)d_in[0];
    const float* mw1    = (const float*)d_in[1];
    const float* mb1    = (const float*)d_in[2];
    const float* mw2    = (const float*)d_in[3];
    const float* mb2    = (const float*)d_in[4];
    const float* mlw    = (const float*)d_in[5];
    const float* mlb    = (const float*)d_in[6];
    const float* mgw    = (const float*)d_in[7];
    const float* mgb    = (const float*)d_in[8];
    const float* mlw2   = (const float*)d_in[9];
    const float* mlb2   = (const float*)d_in[10];
    const float* mgamma = (const float*)d_in[11];
    const float* mbeta  = (const float*)d_in[12];
    const float* w1     = (const float*)d_in[13];
    const float* b1     = (const float*)d_in[14];
    const float* w2     = (const float*)d_in[15];
    const float* b2     = (const float*)d_in[16];
    const float* gw     = (const float*)d_in[17];
    const float* gb     = (const float*)d_in[18];
    const float* lw     = (const float*)d_in[19];
    const float* lb     = (const float*)d_in[20];
    const float* gamma  = (const float*)d_in[21];
    const float* beta   = (const float*)d_in[22];

    float* out  = (float*)d_out;                 // [B,64]
    float* mask = out + (size_t)NB * 64;         // [B,32]

    short* wfrag  = (short*)d_ws;                // 65536 frags (grn weights)
    short* mwfrag = wfrag + (size_t)65536 * 8;   // 24576 frags (mask weights)

    hipLaunchKernelGGL(prep_kernel, dim3(352), dim3(256), 0, stream,
                       w1, w2, gw, lw, mw1, mlw, wfrag);
    hipLaunchKernelGGL(fused_kernel, dim3(NB / 16), dim3(256), 0, stream,
                       x, wfrag, mwfrag,
                       mb1, mw2, mb2, mlb, mgw, mgb, mlw2, mlb2, mgamma, mbeta,
                       b1, b2, gb, lb, gamma, beta,
                       mask, out);
}

// Round 4
// 357.684 us; speedup vs baseline: 2.6147x; 1.0157x over previous
//
#include <hip/hip_runtime.h>
#include <hip/hip_bf16.h>
#include <math.h>

#define NB 16384
#define NF 32
#define ND 64
#define NIN 2048

typedef __attribute__((ext_vector_type(8))) short fragA;   // 8 bf16
typedef __attribute__((ext_vector_type(4))) float fragC;   // 4 fp32

#define MFMA(a, b, c) __builtin_amdgcn_mfma_f32_16x16x32_bf16((a), (b), (c), 0, 0, 0)

__device__ __forceinline__ short f2bf(float f) {
    union { float f; unsigned u; } v; v.f = f;
    return (short)((v.u + 0x7fffu + ((v.u >> 16) & 1u)) >> 16);  // RNE
}
// 8 consecutive fp32 -> bf16 fragment via packed cvt (v_cvt_pk_bf16_f32)
__device__ __forceinline__ fragA cvt8(const float* p) {
    const float4 a = *(const float4*)p;
    const float4 b = *(const float4*)(p + 4);
    union { __hip_bfloat162 h[4]; fragA f; } u;
    u.h[0] = __float22bfloat162_rn(make_float2(a.x, a.y));
    u.h[1] = __float22bfloat162_rn(make_float2(a.z, a.w));
    u.h[2] = __float22bfloat162_rn(make_float2(b.x, b.y));
    u.h[3] = __float22bfloat162_rn(make_float2(b.z, b.w));
    return u.f;
}

// ---------------------------------------------------------------------------
// Prologue: weights -> bf16 B-fragment-linear layout in d_ws (unchanged).
// ---------------------------------------------------------------------------
__global__ __launch_bounds__(256) void prep_kernel(
    const float* __restrict__ w1, const float* __restrict__ w2,
    const float* __restrict__ gw, const float* __restrict__ lw,
    const float* __restrict__ mw1, const float* __restrict__ mlw,
    short* __restrict__ wsout)
{
    int F = blockIdx.x * 256 + threadIdx.x;
    fragA o;
    if (F < 65536) {
        int mat = F >> 14;
        int f   = (F >> 9) & 31;
        int nt  = (F >> 7) & 3;
        int s   = (F >> 6) & 1;
        int l   = F & 63;
        const float* src = (mat == 0 ? w1 : mat == 1 ? w2 : mat == 2 ? gw : lw)
                           + (size_t)f * 4096;
        int n  = nt * 16 + (l & 15);
        int k0 = s * 32 + ((l >> 4) << 3);
#pragma unroll
        for (int j = 0; j < 8; ++j) o[j] = f2bf(src[(k0 + j) * 64 + n]);
    } else {
        int G  = F - 65536;
        int f  = G / 768;
        int r  = G - f * 768;
        int nt = r >> 7;
        int s  = (r >> 6) & 1;
        int l  = r & 63;
        int n  = nt * 16 + (l & 15);
        int k0 = f * 64 + s * 32 + ((l >> 4) << 3);
        if (n < 64) {
#pragma unroll
            for (int j = 0; j < 8; ++j) o[j] = f2bf(mw1[(size_t)(k0 + j) * 64 + n]);
        } else {
#pragma unroll
            for (int j = 0; j < 8; ++j) o[j] = f2bf(mlw[(size_t)(k0 + j) * 32 + (n - 64)]);
        }
    }
    ((fragA*)wsout)[F] = o;
}

// ---------------------------------------------------------------------------
// Fused kernel.  16 rows/block, 4 waves splitting the f-axis (8 each).
// LDS map (floats, total 8960 = 35,840 B -> 4 blocks/CU):
//   [0,1552)      redS   16x97 atomically-accumulated mask partials (ph1)
//                 preS   16x36 at [0,576) after stage A        (ph1 C/D)
//                 hW     4 x 16x68 per-wave h buffers           (ph2)
//   [1552,3600)   wmw2   64x32                                  (ph1)
//   [3600,4624)   wmgw   32x32                                  (ph1)
//   [4624,5648)   wmlw2  32x32                                  (ph1)
//   [4352,8448)   outS   4 x 16x64 output partials              (ph2 tail)
//   [5648,6736)   hS1    16x68                                  (ph1)
//   [6736,7312)   resS   16x36                                  (ph1)
//   [7312,7888)   h2S    16x36                                  (ph1)
//   [8448,8960)   maskS  16x32  (persists ph1 -> ph2)
// ---------------------------------------------------------------------------
__global__ __launch_bounds__(256, 4) void fused_kernel(
    const float* __restrict__ x,
    const short* __restrict__ wfrag, const short* __restrict__ mwfrag,
    const float* __restrict__ mb1, const float* __restrict__ mw2,
    const float* __restrict__ mb2, const float* __restrict__ mlb,
    const float* __restrict__ mgw, const float* __restrict__ mgb,
    const float* __restrict__ mlw2, const float* __restrict__ mlb2,
    const float* __restrict__ mgamma, const float* __restrict__ mbeta,
    const float* __restrict__ b1, const float* __restrict__ b2,
    const float* __restrict__ gb, const float* __restrict__ lb,
    const float* __restrict__ gamma, const float* __restrict__ beta,
    float* __restrict__ mask_out, float* __restrict__ out)
{
    __shared__ float smem[8960];
    float* redS  = smem;
    float* wmw2  = smem + 1552;
    float* wmgw  = smem + 3600;
    float* wmlw2 = smem + 4624;
    float* hS1   = smem + 5648;
    float* resS  = smem + 6736;
    float* h2S   = smem + 7312;
    float* preS  = smem;            // aliases redS (dead after stage A)
    float* maskS = smem + 8448;
    float* outS  = smem + 4352;

    const int tid = threadIdx.x;
    const int w = tid >> 6, l = tid & 63;
    const int row0 = blockIdx.x * 16;
    const int m = l & 15, q = l >> 4;

    const fragA* wf  = (const fragA*)wfrag;
    const fragA* mwf = (const fragA*)mwfrag;

    // zero the shared mask-partial accumulator
    for (int i = tid; i < 1552; i += 256) redS[i] = 0.f;
    __syncthreads();

    // ------------------------- Phase 1: mask -------------------------
    fragC acc[6];
#pragma unroll
    for (int nt = 0; nt < 6; ++nt) acc[nt] = (fragC){0.f, 0.f, 0.f, 0.f};

    const float* xpm = x + (size_t)(row0 + m) * NIN + q * 8;
    for (int fi = 0; fi < 8; ++fi) {
        int f = w * 8 + fi;
        const float* xp = xpm + f * ND;
        fragA a0 = cvt8(xp), a1 = cvt8(xp + 32);
        const size_t fb = (size_t)f * 768 + l;
#pragma unroll
        for (int nt = 0; nt < 6; ++nt) {
            acc[nt] = MFMA(a0, mwf[fb + nt * 128], acc[nt]);
            acc[nt] = MFMA(a1, mwf[fb + nt * 128 + 64], acc[nt]);
        }
    }
    // stage small weights (natural stride 32; reads are broadcasts)
    for (int i = tid; i < 2048; i += 256) wmw2[i] = mw2[i];
    for (int i = tid; i < 1024; i += 256) {
        wmgw[i]  = mgw[i];
        wmlw2[i] = mlw2[i];
    }
    // accumulate partials across waves via LDS atomics
#pragma unroll
    for (int nt = 0; nt < 6; ++nt)
#pragma unroll
        for (int rg = 0; rg < 4; ++rg)
            atomicAdd(&redS[(q * 4 + rg) * 97 + nt * 16 + m], acc[nt][rg]);
    __syncthreads();

    // stage A: h = elu(.+mb1) -> hS1 ; res = .+mlb -> resS
    {
        int r = tid & 15, cb = tid >> 4;
#pragma unroll
        for (int i = 0; i < 6; ++i) {
            int c = cb + i * 16;
            float s = redS[r * 97 + c];
            if (c < 64) {
                float v = s + mb1[c];
                hS1[r * 68 + c] = v > 0.f ? v : expm1f(v);
            } else {
                resS[r * 36 + (c - 64)] = s + mlb[c - 64];
            }
        }
    }
    __syncthreads();

    // stage B: h2 = h @ mw2 + mb2
    {
        int r = tid & 15, c = tid >> 4;
        float h0 = mb2[c], h1 = mb2[c + 16];
        for (int k = 0; k < 64; ++k) {
            float hv = hS1[r * 68 + k];
            h0 += hv * wmw2[k * 32 + c];
            h1 += hv * wmw2[k * 32 + c + 16];
        }
        h2S[r * 36 + c] = h0;
        h2S[r * 36 + c + 16] = h1;
    }
    __syncthreads();

    // stage C: pre = sigmoid(h2@mgw+mgb) * (h2@mlw2+mlb2) + res
    {
        int r = tid & 15, c = tid >> 4;
        float g0 = mgb[c], g1 = mgb[c + 16], l0 = mlb2[c], l1 = mlb2[c + 16];
        for (int k = 0; k < 32; ++k) {
            float hv = h2S[r * 36 + k];
            g0 += hv * wmgw[k * 32 + c];
            g1 += hv * wmgw[k * 32 + c + 16];
            l0 += hv * wmlw2[k * 32 + c];
            l1 += hv * wmlw2[k * 32 + c + 16];
        }
        preS[r * 36 + c]      = l0 / (1.f + expf(-g0)) + resS[r * 36 + c];
        preS[r * 36 + c + 16] = l1 / (1.f + expf(-g1)) + resS[r * 36 + c + 16];
    }
    __syncthreads();

    // stage D: LN(F=32) + softmax (wave 0), mask -> LDS + global
    if (w == 0) {
        int r2 = l >> 2, c0 = (l & 3) * 8;
        float pre[8];
#pragma unroll
        for (int i = 0; i < 8; ++i) pre[i] = preS[r2 * 36 + c0 + i];
        float s1 = 0.f;
#pragma unroll
        for (int i = 0; i < 8; ++i) s1 += pre[i];
        s1 += __shfl_xor(s1, 1); s1 += __shfl_xor(s1, 2);
        float mean = s1 * (1.f / 32.f);
        float s2 = 0.f;
#pragma unroll
        for (int i = 0; i < 8; ++i) { float d = pre[i] - mean; s2 += d * d; }
        s2 += __shfl_xor(s2, 1); s2 += __shfl_xor(s2, 2);
        float inv = rsqrtf(s2 * (1.f / 32.f) + 1e-5f);
        float ln[8]; float mx = -3.4e38f;
#pragma unroll
        for (int i = 0; i < 8; ++i) {
            ln[i] = (pre[i] - mean) * inv * mgamma[c0 + i] + mbeta[c0 + i];
            mx = fmaxf(mx, ln[i]);
        }
        mx = fmaxf(mx, __shfl_xor(mx, 1));
        mx = fmaxf(mx, __shfl_xor(mx, 2));
        float ssum = 0.f;
#pragma unroll
        for (int i = 0; i < 8; ++i) { ln[i] = expf(ln[i] - mx); ssum += ln[i]; }
        ssum += __shfl_xor(ssum, 1); ssum += __shfl_xor(ssum, 2);
        float rs = 1.f / ssum;
        float* mo = mask_out + (size_t)(row0 + r2) * 32 + c0;
        *(float4*)mo       = (float4){ln[0] * rs, ln[1] * rs, ln[2] * rs, ln[3] * rs};
        *(float4*)(mo + 4) = (float4){ln[4] * rs, ln[5] * rs, ln[6] * rs, ln[7] * rs};
#pragma unroll
        for (int i = 0; i < 8; ++i) maskS[r2 * 32 + c0 + i] = ln[i] * rs;
    }
    __syncthreads();

    // ------------------------- Phase 2: GRNs -------------------------
    float* hW = smem + w * 1088;   // per-wave 16x68

    fragC oac[4];
#pragma unroll
    for (int nt = 0; nt < 4; ++nt) oac[nt] = (fragC){0.f, 0.f, 0.f, 0.f};

    for (int fi = 0; fi < 8; ++fi) {
        int f = w * 8 + fi;
        float xres[4][4];
#pragma unroll
        for (int rg = 0; rg < 4; ++rg)
#pragma unroll
            for (int nt = 0; nt < 4; ++nt)
                xres[rg][nt] = x[(size_t)(row0 + q * 4 + rg) * NIN + f * ND + nt * 16 + m];
        float b1v[4], b2v[4], gbv[4], lbv[4], gmv[4], btv[4];
#pragma unroll
        for (int nt = 0; nt < 4; ++nt) {
            int c = f * 64 + nt * 16 + m;
            b1v[nt] = b1[c]; b2v[nt] = b2[c]; gbv[nt] = gb[c];
            lbv[nt] = lb[c]; gmv[nt] = gamma[c]; btv[nt] = beta[c];
        }
        float mk[4];
#pragma unroll
        for (int rg = 0; rg < 4; ++rg) mk[rg] = maskS[(q * 4 + rg) * 32 + f];

        // GEMM1: h1 = elu(x @ w1 + b1) -> hW (A direct from global)
        {
            const float* xp = xpm + f * ND;
            fragA a0 = cvt8(xp), a1 = cvt8(xp + 32);
            const size_t base = (size_t)f * 512 + l;
#pragma unroll
            for (int nt = 0; nt < 4; ++nt) {
                fragC c = {0.f, 0.f, 0.f, 0.f};
                c = MFMA(a0, wf[base + nt * 128], c);
                c = MFMA(a1, wf[base + nt * 128 + 64], c);
                int col = nt * 16 + m;
#pragma unroll
                for (int rg = 0; rg < 4; ++rg) {
                    float v = c[rg] + b1v[nt];
                    hW[(q * 4 + rg) * 68 + col] = v > 0.f ? v : expm1f(v);
                }
            }
        }
        // GEMM2: h2 = h1 @ w2 + b2 -> hW
        {
            const float* ap = hW + m * 68 + q * 8;
            fragA a0 = cvt8(ap), a1 = cvt8(ap + 32);
            const size_t base = ((size_t)(NF + f)) * 512 + l;
            fragC cc[4];
#pragma unroll
            for (int nt = 0; nt < 4; ++nt) {
                fragC c = {0.f, 0.f, 0.f, 0.f};
                c = MFMA(a0, wf[base + nt * 128], c);
                c = MFMA(a1, wf[base + nt * 128 + 64], c);
                cc[nt] = c;
            }
#pragma unroll
            for (int nt = 0; nt < 4; ++nt) {
                int col = nt * 16 + m;
#pragma unroll
                for (int rg = 0; rg < 4; ++rg)
                    hW[(q * 4 + rg) * 68 + col] = cc[nt][rg] + b2v[nt];
            }
        }
        // GEMM3+4 + epilogue
        {
            const float* ap = hW + m * 68 + q * 8;
            fragA a0 = cvt8(ap), a1 = cvt8(ap + 32);
            const size_t baseg = ((size_t)(2 * NF + f)) * 512 + l;
            const size_t basel = ((size_t)(3 * NF + f)) * 512 + l;
            fragC ga[4], la[4];
#pragma unroll
            for (int nt = 0; nt < 4; ++nt) {
                fragC g = {0.f, 0.f, 0.f, 0.f}, li = {0.f, 0.f, 0.f, 0.f};
                g  = MFMA(a0, wf[baseg + nt * 128], g);
                g  = MFMA(a1, wf[baseg + nt * 128 + 64], g);
                li = MFMA(a0, wf[basel + nt * 128], li);
                li = MFMA(a1, wf[basel + nt * 128 + 64], li);
                ga[nt] = g; la[nt] = li;
            }
#pragma unroll
            for (int rg = 0; rg < 4; ++rg) {
                float val[4];
#pragma unroll
                for (int nt = 0; nt < 4; ++nt) {
                    float gg = ga[nt][rg] + gbv[nt];
                    float ll = la[nt][rg] + lbv[nt];
                    val[nt] = ll / (1.f + expf(-gg)) + xres[rg][nt];
                }
                float s1 = val[0] + val[1] + val[2] + val[3];
                s1 += __shfl_xor(s1, 1); s1 += __shfl_xor(s1, 2);
                s1 += __shfl_xor(s1, 4); s1 += __shfl_xor(s1, 8);
                float mean = s1 * (1.f / 64.f);
                float s2 = 0.f;
#pragma unroll
                for (int nt = 0; nt < 4; ++nt) { float d = val[nt] - mean; s2 += d * d; }
                s2 += __shfl_xor(s2, 1); s2 += __shfl_xor(s2, 2);
                s2 += __shfl_xor(s2, 4); s2 += __shfl_xor(s2, 8);
                float inv = rsqrtf(s2 * (1.f / 64.f) + 1e-5f);
#pragma unroll
                for (int nt = 0; nt < 4; ++nt) {
                    float vec = (val[nt] - mean) * inv * gmv[nt] + btv[nt];
                    oac[nt][rg] += mk[rg] * vec;
                }
            }
        }
    }

    // cross-wave output reduction (outS stride 64; other buffers dead)
#pragma unroll
    for (int nt = 0; nt < 4; ++nt)
#pragma unroll
        for (int rg = 0; rg < 4; ++rg)
            outS[w * 1024 + (q * 4 + rg) * 64 + nt * 16 + m] = oac[nt][rg];
    __syncthreads();
    {
        int t4 = tid * 4;
        int r = t4 >> 6, c = t4 & 63;
        float v[4];
#pragma unroll
        for (int j = 0; j < 4; ++j) {
            v[j] = outS[r * 64 + c + j] + outS[1024 + r * 64 + c + j]
                 + outS[2048 + r * 64 + c + j] + outS[3072 + r * 64 + c + j];
        }
        *(float4*)(out + (size_t)(row0 + r) * 64 + c) = (float4){v[0], v[1], v[2], v[3]};
    }
}

// ---------------------------------------------------------------------------
extern "C" void kernel_launch(void* const* d_in, const int* in_sizes, int n_in,
                              void* d_out, int out_size, void* d_ws, size_t ws_size,
                              hipStream_t stream) {
    const float* x      = (const float*)d_in[0];
    const float* mw1    = (const float*)d_in[1];
    const float* mb1    = (const float*)d_in[2];
    const float* mw2    = (const float*)d_in[3];
    const float* mb2    = (const float*)d_in[4];
    const float* mlw    = (const float*)d_in[5];
    const float* mlb    = (const float*)d_in[6];
    const float* mgw    = (const float*)d_in[7];
    const float* mgb    = (const float*)d_in[8];
    const float* mlw2   = (const float*)d_in[9];
    const float* mlb2   = (const float*)d_in[10];
    const float* mgamma = (const float*)d_in[11];
    const float* mbeta  = (const float*)d_in[12];
    const float* w1     = (const float*)d_in[13];
    const float* b1     = (const float*)d_in[14];
    const float* w2     = (const float*)d_in[15];
    const float* b2     = (const float*)d_in[16];
    const float* gw     = (const float*)d_in[17];
    const float* gb     = (const float*)d_in[18];
    const float* lw     = (const float*)d_in[19];
    const float* lb     = (const float*)d_in[20];
    const float* gamma  = (const float*)d_in[21];
    const float* beta   = (const float*)d_in[22];

    float* out  = (float*)d_out;                 // [B,64]
    float* mask = out + (size_t)NB * 64;         // [B,32]

    short* wfrag  = (short*)d_ws;                // 65536 frags (grn weights)
    short* mwfrag = wfrag + (size_t)65536 * 8;   // 24576 frags (mask weights)

    hipLaunchKernelGGL(prep_kernel, dim3(352), dim3(256), 0, stream,
                       w1, w2, gw, lw, mw1, mlw, wfrag);
    hipLaunchKernelGGL(fused_kernel, dim3(NB / 16), dim3(256), 0, stream,
                       x, wfrag, mwfrag,
                       mb1, mw2, mb2, mlb, mgw, mgb, mlw2, mlb2, mgamma, mbeta,
                       b1, b2, gb, lb, gamma, beta,
                       mask, out);
}

// Round 5
// 345.807 us; speedup vs baseline: 2.7045x; 1.0343x over previous
//
#include <hip/hip_runtime.h>
#include <hip/hip_bf16.h>
#include <math.h>

#define NB 16384
#define NF 32
#define ND 64
#define NIN 2048

typedef __attribute__((ext_vector_type(8))) short fragA;   // 8 bf16
typedef __attribute__((ext_vector_type(4))) float fragC;   // 4 fp32

#define MFMA(a, b, c) __builtin_amdgcn_mfma_f32_16x16x32_bf16((a), (b), (c), 0, 0, 0)

__device__ __forceinline__ short f2bf(float f) {
    union { float f; unsigned u; } v; v.f = f;
    return (short)((v.u + 0x7fffu + ((v.u >> 16) & 1u)) >> 16);  // RNE
}
// 8 consecutive fp32 -> bf16 fragment via packed cvt (v_cvt_pk_bf16_f32)
__device__ __forceinline__ fragA cvt8(const float* p) {
    const float4 a = *(const float4*)p;
    const float4 b = *(const float4*)(p + 4);
    union { __hip_bfloat162 h[4]; fragA f; } u;
    u.h[0] = __float22bfloat162_rn(make_float2(a.x, a.y));
    u.h[1] = __float22bfloat162_rn(make_float2(a.z, a.w));
    u.h[2] = __float22bfloat162_rn(make_float2(b.x, b.y));
    u.h[3] = __float22bfloat162_rn(make_float2(b.z, b.w));
    return u.f;
}

// ---------------------------------------------------------------------------
// Prologue: weights -> bf16 B-fragment-linear layout in d_ws.
//   [0, 65536)      : grn w1,w2,gw,lw        (as before)
//   [65536, 90112)  : mask mw1 (n 0..63) ++ mlw (n 64..95)
//   [90112, 90368)  : mw2 64x32   idx = nt*128 + s*64 + l
//   [90368, 90496)  : mgw 32x32   idx = nt*64 + l   (K=32, single chunk)
//   [90496, 90624)  : mlw2 32x32  idx = nt*64 + l
// ---------------------------------------------------------------------------
__global__ __launch_bounds__(256) void prep_kernel(
    const float* __restrict__ w1, const float* __restrict__ w2,
    const float* __restrict__ gw, const float* __restrict__ lw,
    const float* __restrict__ mw1, const float* __restrict__ mlw,
    const float* __restrict__ mw2, const float* __restrict__ mgw,
    const float* __restrict__ mlw2,
    short* __restrict__ wsout)
{
    int F = blockIdx.x * 256 + threadIdx.x;
    fragA o;
    if (F < 65536) {
        int mat = F >> 14;
        int f   = (F >> 9) & 31;
        int nt  = (F >> 7) & 3;
        int s   = (F >> 6) & 1;
        int l   = F & 63;
        const float* src = (mat == 0 ? w1 : mat == 1 ? w2 : mat == 2 ? gw : lw)
                           + (size_t)f * 4096;
        int n  = nt * 16 + (l & 15);
        int k0 = s * 32 + ((l >> 4) << 3);
#pragma unroll
        for (int j = 0; j < 8; ++j) o[j] = f2bf(src[(k0 + j) * 64 + n]);
    } else if (F < 90112) {
        int G  = F - 65536;
        int f  = G / 768;
        int r  = G - f * 768;
        int nt = r >> 7;
        int s  = (r >> 6) & 1;
        int l  = r & 63;
        int n  = nt * 16 + (l & 15);
        int k0 = f * 64 + s * 32 + ((l >> 4) << 3);
        if (n < 64) {
#pragma unroll
            for (int j = 0; j < 8; ++j) o[j] = f2bf(mw1[(size_t)(k0 + j) * 64 + n]);
        } else {
#pragma unroll
            for (int j = 0; j < 8; ++j) o[j] = f2bf(mlw[(size_t)(k0 + j) * 32 + (n - 64)]);
        }
    } else {
        int G2 = F - 90112;
        if (G2 < 256) {
            int nt = G2 >> 7, s = (G2 >> 6) & 1, l = G2 & 63;
            int n = nt * 16 + (l & 15);
            int k0 = s * 32 + ((l >> 4) << 3);
#pragma unroll
            for (int j = 0; j < 8; ++j) o[j] = f2bf(mw2[(k0 + j) * 32 + n]);
        } else {
            int G3 = G2 - 256;
            const float* src = (G3 < 128) ? mgw : mlw2;
            G3 &= 127;
            int nt = G3 >> 6, l = G3 & 63;
            int n = nt * 16 + (l & 15);
            int k0 = (l >> 4) << 3;
#pragma unroll
            for (int j = 0; j < 8; ++j) o[j] = f2bf(src[(k0 + j) * 32 + n]);
        }
    }
    ((fragA*)wsout)[F] = o;
}

// ---------------------------------------------------------------------------
// Fused kernel.  16 rows/block, 4 waves splitting the f-axis (8 each).
// LDS map (floats, total 8960 = 35,840 B -> 4 blocks/CU, grid-capped anyway):
//   phase 1:
//     redS  [0,1552)     16x97 atomic mask partials (dead after stage A)
//     gS    [0,640)      16x36 gate pre-acts    (stage C, aliases redS)
//     lS    [768,1408)   16x36 lin pre-acts     (stage C, aliases redS)
//     hS1   [1552,2640)  16x68 elu(h1)
//     resS  [2640,3216)  16x36 skip path
//     h2S   [3216,3792)  16x36 h2
//   phase 2:
//     hW    [0,4352)     4 x 16x68 per-wave h buffers
//     outS  [4352,8448)  4 x 16x64 output partials
//   maskS   [8448,8960)  persists phase 1 -> phase 2
// ---------------------------------------------------------------------------
__global__ __launch_bounds__(256, 4) void fused_kernel(
    const float* __restrict__ x,
    const short* __restrict__ wfrag, const short* __restrict__ mwfrag,
    const short* __restrict__ swfrag,
    const float* __restrict__ mb1, const float* __restrict__ mb2,
    const float* __restrict__ mlb, const float* __restrict__ mgb,
    const float* __restrict__ mlb2,
    const float* __restrict__ mgamma, const float* __restrict__ mbeta,
    const float* __restrict__ b1, const float* __restrict__ b2,
    const float* __restrict__ gb, const float* __restrict__ lb,
    const float* __restrict__ gamma, const float* __restrict__ beta,
    float* __restrict__ mask_out, float* __restrict__ out)
{
    __shared__ float smem[8960];
    float* redS  = smem;
    float* gS    = smem;
    float* lS    = smem + 768;
    float* hS1   = smem + 1552;
    float* resS  = smem + 2640;
    float* h2S   = smem + 3216;
    float* outS  = smem + 4352;
    float* maskS = smem + 8448;

    const int tid = threadIdx.x;
    const int w = tid >> 6, l = tid & 63;
    const int row0 = blockIdx.x * 16;
    const int m = l & 15, q = l >> 4;

    const fragA* wf  = (const fragA*)wfrag;
    const fragA* mwf = (const fragA*)mwfrag;
    const fragA* swf = (const fragA*)swfrag;

    // zero the shared mask-partial accumulator
    for (int i = tid; i < 1552; i += 256) redS[i] = 0.f;
    __syncthreads();

    // ------------------------- Phase 1: mask -------------------------
    fragC acc[6];
#pragma unroll
    for (int nt = 0; nt < 6; ++nt) acc[nt] = (fragC){0.f, 0.f, 0.f, 0.f};

    const float* xpm = x + (size_t)(row0 + m) * NIN + q * 8;
    for (int fi = 0; fi < 8; ++fi) {
        int f = w * 8 + fi;
        const float* xp = xpm + f * ND;
        fragA a0 = cvt8(xp), a1 = cvt8(xp + 32);
        const size_t fb = (size_t)f * 768 + l;
#pragma unroll
        for (int nt = 0; nt < 6; ++nt) {
            acc[nt] = MFMA(a0, mwf[fb + nt * 128], acc[nt]);
            acc[nt] = MFMA(a1, mwf[fb + nt * 128 + 64], acc[nt]);
        }
    }
    // accumulate partials across waves via LDS atomics
#pragma unroll
    for (int nt = 0; nt < 6; ++nt)
#pragma unroll
        for (int rg = 0; rg < 4; ++rg)
            atomicAdd(&redS[(q * 4 + rg) * 97 + nt * 16 + m], acc[nt][rg]);
    __syncthreads();

    // stage A: h = elu(.+mb1) -> hS1 ; res = .+mlb -> resS
    {
        int r = tid & 15, cb = tid >> 4;
#pragma unroll
        for (int i = 0; i < 6; ++i) {
            int c = cb + i * 16;
            float s = redS[r * 97 + c];
            if (c < 64) {
                float v = s + mb1[c];
                hS1[r * 68 + c] = v > 0.f ? v : expm1f(v);
            } else {
                resS[r * 36 + (c - 64)] = s + mlb[c - 64];
            }
        }
    }
    __syncthreads();

    // stage B (MFMA, waves 0-1): h2 = h @ mw2 + mb2 -> h2S
    if (w < 2) {
        const float* ap = hS1 + m * 68 + q * 8;
        fragA a0 = cvt8(ap), a1 = cvt8(ap + 32);
        fragC c = {0.f, 0.f, 0.f, 0.f};
        c = MFMA(a0, swf[w * 128 + l], c);
        c = MFMA(a1, swf[w * 128 + 64 + l], c);
        float bv = mb2[w * 16 + m];
#pragma unroll
        for (int rg = 0; rg < 4; ++rg)
            h2S[(q * 4 + rg) * 36 + w * 16 + m] = c[rg] + bv;
    }
    __syncthreads();

    // stage C (MFMA, all waves): gate (waves 0-1) / lin (waves 2-3) pre-acts
    {
        int ntc = w & 1;
        int isl = w >> 1;
        fragA a = cvt8(h2S + m * 36 + q * 8);          // K=32
        fragC c = {0.f, 0.f, 0.f, 0.f};
        c = MFMA(a, swf[256 + isl * 128 + ntc * 64 + l], c);
        float* dst = isl ? lS : gS;
#pragma unroll
        for (int rg = 0; rg < 4; ++rg)
            dst[(q * 4 + rg) * 36 + ntc * 16 + m] = c[rg];
    }
    __syncthreads();

    // stage D: pre = sigmoid(g+mgb)*(l+mlb2)+res ; LN(F=32)+softmax (wave 0)
    if (w == 0) {
        int r2 = l >> 2, c0 = (l & 3) * 8;
        float pre[8];
#pragma unroll
        for (int i = 0; i < 8; ++i) {
            int c = c0 + i;
            float gg = gS[r2 * 36 + c] + mgb[c];
            float ll = lS[r2 * 36 + c] + mlb2[c];
            pre[i] = ll / (1.f + expf(-gg)) + resS[r2 * 36 + c];
        }
        float s1 = 0.f;
#pragma unroll
        for (int i = 0; i < 8; ++i) s1 += pre[i];
        s1 += __shfl_xor(s1, 1); s1 += __shfl_xor(s1, 2);
        float mean = s1 * (1.f / 32.f);
        float s2 = 0.f;
#pragma unroll
        for (int i = 0; i < 8; ++i) { float d = pre[i] - mean; s2 += d * d; }
        s2 += __shfl_xor(s2, 1); s2 += __shfl_xor(s2, 2);
        float inv = rsqrtf(s2 * (1.f / 32.f) + 1e-5f);
        float ln[8]; float mx = -3.4e38f;
#pragma unroll
        for (int i = 0; i < 8; ++i) {
            ln[i] = (pre[i] - mean) * inv * mgamma[c0 + i] + mbeta[c0 + i];
            mx = fmaxf(mx, ln[i]);
        }
        mx = fmaxf(mx, __shfl_xor(mx, 1));
        mx = fmaxf(mx, __shfl_xor(mx, 2));
        float ssum = 0.f;
#pragma unroll
        for (int i = 0; i < 8; ++i) { ln[i] = expf(ln[i] - mx); ssum += ln[i]; }
        ssum += __shfl_xor(ssum, 1); ssum += __shfl_xor(ssum, 2);
        float rs = 1.f / ssum;
        float* mo = mask_out + (size_t)(row0 + r2) * 32 + c0;
        *(float4*)mo       = (float4){ln[0] * rs, ln[1] * rs, ln[2] * rs, ln[3] * rs};
        *(float4*)(mo + 4) = (float4){ln[4] * rs, ln[5] * rs, ln[6] * rs, ln[7] * rs};
#pragma unroll
        for (int i = 0; i < 8; ++i) maskS[r2 * 32 + c0 + i] = ln[i] * rs;
    }
    __syncthreads();

    // ------------------------- Phase 2: GRNs -------------------------
    float* hW = smem + w * 1088;   // per-wave 16x68

    fragC oac[4];
#pragma unroll
    for (int nt = 0; nt < 4; ++nt) oac[nt] = (fragC){0.f, 0.f, 0.f, 0.f};

    for (int fi = 0; fi < 8; ++fi) {
        int f = w * 8 + fi;
        float xres[4][4];
#pragma unroll
        for (int rg = 0; rg < 4; ++rg)
#pragma unroll
            for (int nt = 0; nt < 4; ++nt)
                xres[rg][nt] = x[(size_t)(row0 + q * 4 + rg) * NIN + f * ND + nt * 16 + m];
        float b1v[4], b2v[4], gbv[4], lbv[4], gmv[4], btv[4];
#pragma unroll
        for (int nt = 0; nt < 4; ++nt) {
            int c = f * 64 + nt * 16 + m;
            b1v[nt] = b1[c]; b2v[nt] = b2[c]; gbv[nt] = gb[c];
            lbv[nt] = lb[c]; gmv[nt] = gamma[c]; btv[nt] = beta[c];
        }
        float mk[4];
#pragma unroll
        for (int rg = 0; rg < 4; ++rg) mk[rg] = maskS[(q * 4 + rg) * 32 + f];

        // GEMM1: h1 = elu(x @ w1 + b1) -> hW (A direct from global)
        {
            const float* xp = xpm + f * ND;
            fragA a0 = cvt8(xp), a1 = cvt8(xp + 32);
            const size_t base = (size_t)f * 512 + l;
#pragma unroll
            for (int nt = 0; nt < 4; ++nt) {
                fragC c = {0.f, 0.f, 0.f, 0.f};
                c = MFMA(a0, wf[base + nt * 128], c);
                c = MFMA(a1, wf[base + nt * 128 + 64], c);
                int col = nt * 16 + m;
#pragma unroll
                for (int rg = 0; rg < 4; ++rg) {
                    float v = c[rg] + b1v[nt];
                    hW[(q * 4 + rg) * 68 + col] = v > 0.f ? v : expm1f(v);
                }
            }
        }
        // GEMM2: h2 = h1 @ w2 + b2 -> hW
        {
            const float* ap = hW + m * 68 + q * 8;
            fragA a0 = cvt8(ap), a1 = cvt8(ap + 32);
            const size_t base = ((size_t)(NF + f)) * 512 + l;
            fragC cc[4];
#pragma unroll
            for (int nt = 0; nt < 4; ++nt) {
                fragC c = {0.f, 0.f, 0.f, 0.f};
                c = MFMA(a0, wf[base + nt * 128], c);
                c = MFMA(a1, wf[base + nt * 128 + 64], c);
                cc[nt] = c;
            }
#pragma unroll
            for (int nt = 0; nt < 4; ++nt) {
                int col = nt * 16 + m;
#pragma unroll
                for (int rg = 0; rg < 4; ++rg)
                    hW[(q * 4 + rg) * 68 + col] = cc[nt][rg] + b2v[nt];
            }
        }
        // GEMM3+4 + epilogue
        {
            const float* ap = hW + m * 68 + q * 8;
            fragA a0 = cvt8(ap), a1 = cvt8(ap + 32);
            const size_t baseg = ((size_t)(2 * NF + f)) * 512 + l;
            const size_t basel = ((size_t)(3 * NF + f)) * 512 + l;
            fragC ga[4], la[4];
#pragma unroll
            for (int nt = 0; nt < 4; ++nt) {
                fragC g = {0.f, 0.f, 0.f, 0.f}, li = {0.f, 0.f, 0.f, 0.f};
                g  = MFMA(a0, wf[baseg + nt * 128], g);
                g  = MFMA(a1, wf[baseg + nt * 128 + 64], g);
                li = MFMA(a0, wf[basel + nt * 128], li);
                li = MFMA(a1, wf[basel + nt * 128 + 64], li);
                ga[nt] = g; la[nt] = li;
            }
#pragma unroll
            for (int rg = 0; rg < 4; ++rg) {
                float val[4];
#pragma unroll
                for (int nt = 0; nt < 4; ++nt) {
                    float gg = ga[nt][rg] + gbv[nt];
                    float ll = la[nt][rg] + lbv[nt];
                    val[nt] = ll / (1.f + expf(-gg)) + xres[rg][nt];
                }
                float s1 = val[0] + val[1] + val[2] + val[3];
                s1 += __shfl_xor(s1, 1); s1 += __shfl_xor(s1, 2);
                s1 += __shfl_xor(s1, 4); s1 += __shfl_xor(s1, 8);
                float mean = s1 * (1.f / 64.f);
                float s2 = 0.f;
#pragma unroll
                for (int nt = 0; nt < 4; ++nt) { float d = val[nt] - mean; s2 += d * d; }
                s2 += __shfl_xor(s2, 1); s2 += __shfl_xor(s2, 2);
                s2 += __shfl_xor(s2, 4); s2 += __shfl_xor(s2, 8);
                float inv = rsqrtf(s2 * (1.f / 64.f) + 1e-5f);
#pragma unroll
                for (int nt = 0; nt < 4; ++nt) {
                    float vec = (val[nt] - mean) * inv * gmv[nt] + btv[nt];
                    oac[nt][rg] += mk[rg] * vec;
                }
            }
        }
    }

    // cross-wave output reduction
#pragma unroll
    for (int nt = 0; nt < 4; ++nt)
#pragma unroll
        for (int rg = 0; rg < 4; ++rg)
            outS[w * 1024 + (q * 4 + rg) * 64 + nt * 16 + m] = oac[nt][rg];
    __syncthreads();
    {
        int t4 = tid * 4;
        int r = t4 >> 6, c = t4 & 63;
        float v[4];
#pragma unroll
        for (int j = 0; j < 4; ++j) {
            v[j] = outS[r * 64 + c + j] + outS[1024 + r * 64 + c + j]
                 + outS[2048 + r * 64 + c + j] + outS[3072 + r * 64 + c + j];
        }
        *(float4*)(out + (size_t)(row0 + r) * 64 + c) = (float4){v[0], v[1], v[2], v[3]};
    }
}

// ---------------------------------------------------------------------------
extern "C" void kernel_launch(void* const* d_in, const int* in_sizes, int n_in,
                              void* d_out, int out_size, void* d_ws, size_t ws_size,
                              hipStream_t stream) {
    const float* x      = (const float*)d_in[0];
    const float* mw1    = (const float*)d_in[1];
    const float* mb1    = (const float*)d_in[2];
    const float* mw2    = (const float*)d_in[3];
    const float* mb2    = (const float*)d_in[4];
    const float* mlw    = (const float*)d_in[5];
    const float* mlb    = (const float*)d_in[6];
    const float* mgw    = (const float*)d_in[7];
    const float* mgb    = (const float*)d_in[8];
    const float* mlw2   = (const float*)d_in[9];
    const float* mlb2   = (const float*)d_in[10];
    const float* mgamma = (const float*)d_in[11];
    const float* mbeta  = (const float*)d_in[12];
    const float* w1     = (const float*)d_in[13];
    const float* b1     = (const float*)d_in[14];
    const float* w2     = (const float*)d_in[15];
    const float* b2     = (const float*)d_in[16];
    const float* gw     = (const float*)d_in[17];
    const float* gb     = (const float*)d_in[18];
    const float* lw     = (const float*)d_in[19];
    const float* lb     = (const float*)d_in[20];
    const float* gamma  = (const float*)d_in[21];
    const float* beta   = (const float*)d_in[22];

    float* out  = (float*)d_out;                 // [B,64]
    float* mask = out + (size_t)NB * 64;         // [B,32]

    short* wfrag  = (short*)d_ws;                // 65536 frags (grn weights)
    short* mwfrag = wfrag + (size_t)65536 * 8;   // 24576 frags (mask big GEMM)
    short* swfrag = wfrag + (size_t)90112 * 8;   // 512 frags (mw2/mgw/mlw2)

    hipLaunchKernelGGL(prep_kernel, dim3(354), dim3(256), 0, stream,
                       w1, w2, gw, lw, mw1, mlw, mw2, mgw, mlw2, wfrag);
    hipLaunchKernelGGL(fused_kernel, dim3(NB / 16), dim3(256), 0, stream,
                       x, wfrag, mwfrag, swfrag,
                       mb1, mb2, mlb, mgb, mlb2, mgamma, mbeta,
                       b1, b2, gb, lb, gamma, beta,
                       mask, out);
}